// Round 6
// baseline (1196.357 us; speedup 1.0000x reference)
//
#include <hip/hip_runtime.h>
#include <math.h>

#define D_TOT 480

typedef short bf16x8 __attribute__((ext_vector_type(8)));
typedef float f32x4 __attribute__((ext_vector_type(4)));

#define MFMA16(a, b, c) __builtin_amdgcn_mfma_f32_16x16x32_bf16((a), (b), (c), 0, 0, 0)

static __device__ __forceinline__ unsigned short f2bf(float x) {
  unsigned u = __float_as_uint(x);
  u += 0x7FFFu + ((u >> 16) & 1u);   // RNE (inputs finite)
  return (unsigned short)(u >> 16);
}
static __device__ __forceinline__ float bf2f(unsigned short v) {
  return __uint_as_float(((unsigned)v) << 16);
}

// ---------------------------------------------------------------------------
// K0: Mtmp_b = (Wq_b . Wd_b . Wk_b^T) * scale_b (fp32), scale folds all norms:
//   scale_b = 1 / (m^2 * sqrt(1440*d)).
// ws fp32 layout: M0 [0,16384), M1 [16384,20480), M2 [20480,21504)
// ---------------------------------------------------------------------------
__global__ __launch_bounds__(256) void precompute_M(
    const float* __restrict__ Wq0, const float* __restrict__ Wq1, const float* __restrict__ Wq2,
    const float* __restrict__ Wk0, const float* __restrict__ Wk1, const float* __restrict__ Wk2,
    const float* __restrict__ Wd0, const float* __restrict__ Wd1, const float* __restrict__ Wd2,
    float* __restrict__ ws) {
  __shared__ float T[16 * 128];
  int b = blockIdx.x;
  const float *Wq, *Wk, *Wd;
  float* M;
  int m, deg, strip;
  if (b < 8)       { Wq = Wq0; Wk = Wk0; Wd = Wd0; M = ws;         m = 128; deg = 1; strip = b; }
  else if (b < 12) { Wq = Wq1; Wk = Wk1; Wd = Wd1; M = ws + 16384; m = 64;  deg = 3; strip = b - 8; }
  else if (b < 14) { Wq = Wq2; Wk = Wk2; Wd = Wd2; M = ws + 20480; m = 32;  deg = 5; strip = b - 12; }
  else return;
  int r0 = strip * 16;
  if (r0 >= m) return;
  float scale = 1.0f / ((float)m * (float)m * sqrtf(1440.0f * (float)deg));
  for (int idx = threadIdx.x; idx < 16 * m; idx += 256) {
    int r = idx / m, c = idx % m;
    float s = 0.f;
    for (int a = 0; a < m; ++a) s += Wq[(r0 + r) * m + a] * Wd[a * m + c];
    T[r * m + c] = s;
  }
  __syncthreads();
  for (int idx = threadIdx.x; idx < 16 * m; idx += 256) {
    int r = idx / m, j = idx % m;
    float s = 0.f;
    for (int c = 0; c < m; ++c) s += T[r * m + c] * Wk[j * m + c];
    M[(r0 + r) * m + j] = s * scale;
  }
}

// ---------------------------------------------------------------------------
// K0b: pack B = [M_b | Wv_b/sqrt(m)] (bf16) in per-MFMA-fragment layout.
// Fragment = 1 KB: elem (l,j) = B[k = kt*32+(l>>4)*8+j][c = ct*16+(l&15)].
// ---------------------------------------------------------------------------
__global__ __launch_bounds__(256) void pack_B(
    const float* __restrict__ Mtmp,
    const float* __restrict__ Wv0, const float* __restrict__ Wv1, const float* __restrict__ Wv2,
    unsigned short* __restrict__ Bp) {
  int idx = blockIdx.x * 256 + threadIdx.x;
  if (idx >= 43008) return;
  float val;
  if (idx < 32768) {
    int fragi = idx >> 9, rem = idx & 511;
    int l = rem >> 3, j = rem & 7;
    int ct = fragi >> 2, kt = fragi & 3;
    int k = kt * 32 + (l >> 4) * 8 + j;
    int c = ct * 16 + (l & 15);
    val = (c < 128) ? Mtmp[k * 128 + c] : Wv0[k * 128 + (c - 128)] * 0.08838834764831845f;
  } else if (idx < 40960) {
    int i1 = idx - 32768;
    int fragi = i1 >> 9, rem = i1 & 511;
    int l = rem >> 3, j = rem & 7;
    int ct = fragi >> 1, kt = fragi & 1;
    int k = kt * 32 + (l >> 4) * 8 + j;
    int c = ct * 16 + (l & 15);
    val = (c < 64) ? Mtmp[16384 + k * 64 + c] : Wv1[k * 64 + (c - 64)] * 0.125f;
  } else {
    int i2 = idx - 40960;
    int ct = i2 >> 9, rem = i2 & 511;
    int l = rem >> 3, j = rem & 7;
    int k = (l >> 4) * 8 + j;
    int c = ct * 16 + (l & 15);
    val = (c < 32) ? Mtmp[20480 + k * 32 + c] : Wv2[k * 32 + (c - 32)] * 0.17677669529663687f;
  }
  Bp[idx] = f2bf(val);
}

// ---------------------------------------------------------------------------
// K0c: gptr[g] = lower_bound(batch, g)  (batch sorted ascending)
// ---------------------------------------------------------------------------
__global__ __launch_bounds__(256) void build_gptr(
    const int* __restrict__ batch, int* __restrict__ gptr, int N, int G) {
  int g = blockIdx.x * 256 + threadIdx.x;
  if (g > G) return;
  int lo = 0, hi = N;
  while (lo < hi) {
    int mid = (lo + hi) >> 1;
    if (batch[mid] < g) lo = mid + 1; else hi = mid;
  }
  gptr[g] = lo;
}

// ---------------------------------------------------------------------------
// K0d: per-graph item counts (items = 64-node graph-aligned chunks),
// exclusive prefix sum (single block, G <= 1024), total item count.
// ---------------------------------------------------------------------------
__global__ __launch_bounds__(1024) void build_items_meta(
    const int* __restrict__ gptr, int* __restrict__ itembase,
    int* __restrict__ ntot, int G) {
  __shared__ int sc[1024];
  int g = threadIdx.x;
  int ni = 0;
  if (g < G) ni = (gptr[g + 1] - gptr[g] + 63) >> 6;
  sc[g] = ni;
  __syncthreads();
  for (int off = 1; off < 1024; off <<= 1) {
    int v = (g >= off) ? sc[g - off] : 0;
    __syncthreads();
    sc[g] += v;
    __syncthreads();
  }
  if (g < G) itembase[g] = sc[g] - ni;   // exclusive
  if (g == 0) { itembase[G] = sc[G - 1]; *ntot = sc[G - 1]; }
}

// ---------------------------------------------------------------------------
// K0e: expand work list: items[i] = (start_node, count<=64), graph-aligned.
// ---------------------------------------------------------------------------
__global__ __launch_bounds__(256) void fill_items(
    const int* __restrict__ gptr, const int* __restrict__ itembase,
    int2* __restrict__ items, int G) {
  int g = blockIdx.x * 256 + threadIdx.x;
  if (g >= G) return;
  int s = gptr[g], cnt = gptr[g + 1] - s;
  int base = itembase[g];
  int ni = (cnt + 63) >> 6;
  for (int k = 0; k < ni; ++k)
    items[base + k] = make_int2(s + 64 * k, min(64, cnt - 64 * k));
}

// ---------------------------------------------------------------------------
// Phase A: one 64-node single-graph item per wave, 4 sub-tiles of 16.
// R4's proven memory structure: wave-private LDS x-tile (natural layout,
// XOR swizzle), coalesced float4 staging, A-frag register gather, B-frags
// from global (L2-resident). NO atomics, NO segmentation: plain partial
// store (480 cols + norm) to scratch[item].
// ---------------------------------------------------------------------------
__global__ __launch_bounds__(256, 2) void fused_partial_kernel(
    const float* __restrict__ f, const unsigned short* __restrict__ Bpack,
    const int2* __restrict__ items, const int* __restrict__ ntot,
    float* __restrict__ scratch) {
  __shared__ __align__(16) unsigned short xs_all[4 * 8192];
  int t = threadIdx.x, w = t >> 6, lane = t & 63;
  char* xsb = (char*)(xs_all + w * 8192);

  int item = blockIdx.x * 4 + w;
  if (item >= *ntot) return;
  int2 it = items[item];
  int start = it.x, count = it.y;

  int q = lane >> 4, lm = lane & 15;
  unsigned swzlm = (unsigned)((lm & 7) << 4);

  const bf16x8* B0f = (const bf16x8*)Bpack;
  const bf16x8* B1f = (const bf16x8*)(Bpack + 32768);
  const bf16x8* B2f = (const bf16x8*)(Bpack + 40960);

  float r0[8], r1[3][4], r2[5][2], naccw = 0.f;
#pragma unroll
  for (int i = 0; i < 8; ++i) r0[i] = 0.f;
#pragma unroll
  for (int d = 0; d < 3; ++d)
#pragma unroll
    for (int i = 0; i < 4; ++i) r1[d][i] = 0.f;
#pragma unroll
  for (int d = 0; d < 5; ++d)
#pragma unroll
    for (int i = 0; i < 2; ++i) r2[d][i] = 0.f;

  for (int st = 0; st < count; st += 16) {
    int nt = start + st;
    int valid = min(16, count - st);

    // ---- stage: 16 nodes x 480 fp32 -> natural bf16 rows (swizzled) ----
    {
      int ns = lane >> 2, e0 = lane & 3;
      const float* frow = f + (size_t)(nt + ns) * 480;
      char* wrow = xsb + ns * 1024;
      unsigned swzw = (unsigned)((ns & 7) << 4);
      bool okn = ns < valid;
#pragma unroll
      for (int i = 0; i < 30; ++i) {
        int e4 = e0 + i * 4;
        float4 xv = make_float4(0.f, 0.f, 0.f, 0.f);
        if (okn) xv = reinterpret_cast<const float4*>(frow)[e4];
        unsigned p0 = (unsigned)f2bf(xv.x) | ((unsigned)f2bf(xv.y) << 16);
        unsigned p1 = (unsigned)f2bf(xv.z) | ((unsigned)f2bf(xv.w) << 16);
        *reinterpret_cast<uint2*>(wrow + (((unsigned)(e4 * 8)) ^ swzw)) = make_uint2(p0, p1);
      }
    }

    // ---- gather A-frags into registers (row = lm, k-chunk = q) ----
    const char* arow = xsb + lm * 1024;
    bf16x8 a0[4];
#pragma unroll
    for (int ks = 0; ks < 4; ++ks)
      a0[ks] = *reinterpret_cast<const bf16x8*>(arow + (((unsigned)(ks * 64 + q * 16)) ^ swzlm));
    bf16x8 a1[3][2];
#pragma unroll
    for (int d = 0; d < 3; ++d)
#pragma unroll
      for (int h = 0; h < 2; ++h) {
        bf16x8 v;
#pragma unroll
        for (int j = 0; j < 8; ++j) {
          int km = h * 32 + q * 8 + j;
          unsigned off = ((unsigned)(2 * (128 + 3 * km + d))) ^ swzlm;
          v[j] = (short)*reinterpret_cast<const unsigned short*>(arow + off);
        }
        a1[d][h] = v;
      }
    bf16x8 a2[5];
#pragma unroll
    for (int d = 0; d < 5; ++d) {
      bf16x8 v;
#pragma unroll
      for (int j = 0; j < 8; ++j) {
        int km = q * 8 + j;
        unsigned off = ((unsigned)(2 * (320 + 5 * km + d))) ^ swzlm;
        v[j] = (short)*reinterpret_cast<const unsigned short*>(arow + off);
      }
      a2[d] = v;
    }

    // x read in C-frag order: node = q*4+r, natural col c (same-wave LDS)
    auto ldx = [&](int node, int c) -> float {
      unsigned off = ((unsigned)(2 * c)) ^ ((unsigned)((node & 7) << 4));
      return bf2f(*reinterpret_cast<const unsigned short*>(xsb + node * 1024 + off));
    };

    // ---- u-phase: logits ----
    float pl0 = 0.f, pl1 = 0.f, pl2 = 0.f, pl3 = 0.f;
#pragma unroll
    for (int ct = 0; ct < 8; ++ct) {
      f32x4 u = {0.f, 0.f, 0.f, 0.f};
      u = MFMA16(a0[0], B0f[(ct * 4 + 0) * 64 + lane], u);
      u = MFMA16(a0[1], B0f[(ct * 4 + 1) * 64 + lane], u);
      u = MFMA16(a0[2], B0f[(ct * 4 + 2) * 64 + lane], u);
      u = MFMA16(a0[3], B0f[(ct * 4 + 3) * 64 + lane], u);
      int c = ct * 16 + lm;
      pl0 += u[0] * ldx(q * 4 + 0, c);
      pl1 += u[1] * ldx(q * 4 + 1, c);
      pl2 += u[2] * ldx(q * 4 + 2, c);
      pl3 += u[3] * ldx(q * 4 + 3, c);
    }
#pragma unroll
    for (int d = 0; d < 3; ++d)
#pragma unroll
      for (int ct = 0; ct < 4; ++ct) {
        f32x4 u = {0.f, 0.f, 0.f, 0.f};
        u = MFMA16(a1[d][0], B1f[(ct * 2 + 0) * 64 + lane], u);
        u = MFMA16(a1[d][1], B1f[(ct * 2 + 1) * 64 + lane], u);
        int c = 128 + 3 * (ct * 16 + lm) + d;
        pl0 += u[0] * ldx(q * 4 + 0, c);
        pl1 += u[1] * ldx(q * 4 + 1, c);
        pl2 += u[2] * ldx(q * 4 + 2, c);
        pl3 += u[3] * ldx(q * 4 + 3, c);
      }
#pragma unroll
    for (int d = 0; d < 5; ++d)
#pragma unroll
      for (int ct = 0; ct < 2; ++ct) {
        f32x4 u = {0.f, 0.f, 0.f, 0.f};
        u = MFMA16(a2[d], B2f[ct * 64 + lane], u);
        int c = 320 + 5 * (ct * 16 + lm) + d;
        pl0 += u[0] * ldx(q * 4 + 0, c);
        pl1 += u[1] * ldx(q * 4 + 1, c);
        pl2 += u[2] * ldx(q * 4 + 2, c);
        pl3 += u[3] * ldx(q * 4 + 3, c);
      }
#pragma unroll
    for (int off = 1; off < 16; off <<= 1) {
      pl0 += __shfl_xor(pl0, off);
      pl1 += __shfl_xor(pl1, off);
      pl2 += __shfl_xor(pl2, off);
      pl3 += __shfl_xor(pl3, off);
    }
    float w0 = (q * 4 + 0 < valid) ? __expf(pl0) : 0.f;
    float w1 = (q * 4 + 1 < valid) ? __expf(pl1) : 0.f;
    float w2 = (q * 4 + 2 < valid) ? __expf(pl2) : 0.f;
    float w3 = (q * 4 + 3 < valid) ? __expf(pl3) : 0.f;

    // ---- v-pass (whole item is one graph: single weighted pass) ----
    if (lm == 0) naccw += w0 + w1 + w2 + w3;
#pragma unroll
    for (int ct = 0; ct < 8; ++ct) {
      f32x4 v = {0.f, 0.f, 0.f, 0.f};
      v = MFMA16(a0[0], B0f[((ct + 8) * 4 + 0) * 64 + lane], v);
      v = MFMA16(a0[1], B0f[((ct + 8) * 4 + 1) * 64 + lane], v);
      v = MFMA16(a0[2], B0f[((ct + 8) * 4 + 2) * 64 + lane], v);
      v = MFMA16(a0[3], B0f[((ct + 8) * 4 + 3) * 64 + lane], v);
      r0[ct] += w0 * v[0] + w1 * v[1] + w2 * v[2] + w3 * v[3];
    }
#pragma unroll
    for (int d = 0; d < 3; ++d)
#pragma unroll
      for (int ct = 0; ct < 4; ++ct) {
        f32x4 v = {0.f, 0.f, 0.f, 0.f};
        v = MFMA16(a1[d][0], B1f[((ct + 4) * 2 + 0) * 64 + lane], v);
        v = MFMA16(a1[d][1], B1f[((ct + 4) * 2 + 1) * 64 + lane], v);
        r1[d][ct] += w0 * v[0] + w1 * v[1] + w2 * v[2] + w3 * v[3];
      }
#pragma unroll
    for (int d = 0; d < 5; ++d)
#pragma unroll
      for (int ct = 0; ct < 2; ++ct) {
        f32x4 v = {0.f, 0.f, 0.f, 0.f};
        v = MFMA16(a2[d], B2f[(ct + 2) * 64 + lane], v);
        r2[d][ct] += w0 * v[0] + w1 * v[1] + w2 * v[2] + w3 * v[3];
      }
  }

  // ---- wave reduce across q, plain coalesced partial store ----
  auto wavered = [&](float s) -> float {
    s += __shfl_xor(s, 16);
    s += __shfl_xor(s, 32);
    return s;
  };
  float* pout = scratch + (size_t)item * 512;
#pragma unroll
  for (int ct = 0; ct < 8; ++ct) {
    float s = wavered(r0[ct]);
    if (lane < 16) pout[ct * 16 + lane] = s;
  }
#pragma unroll
  for (int d = 0; d < 3; ++d)
#pragma unroll
    for (int ct = 0; ct < 4; ++ct) {
      float s = wavered(r1[d][ct]);
      if (lane < 16) pout[128 + 3 * (ct * 16 + lane) + d] = s;
    }
#pragma unroll
  for (int d = 0; d < 5; ++d)
#pragma unroll
    for (int ct = 0; ct < 2; ++ct) {
      float s = wavered(r2[d][ct]);
      if (lane < 16) pout[320 + 5 * (ct * 16 + lane) + d] = s;
    }
  {
    float s = wavered(naccw);
    if (lane == 0) pout[480] = s;
  }
}

// ---------------------------------------------------------------------------
// Phase B: block per graph, sum partials, divide by clipped norm, store.
// ---------------------------------------------------------------------------
__global__ __launch_bounds__(256) void reduce_kernel(
    const float* __restrict__ scratch, const int* __restrict__ itembase,
    float* __restrict__ out, int G) {
  __shared__ float snrm;
  int g = blockIdx.x;
  int i0 = itembase[g], i1 = itembase[g + 1];
  int t = threadIdx.x;
  float a0 = 0.f, a1 = 0.f;
  int c1 = t + 256;
  for (int it = i0; it < i1; ++it) {
    const float* p = scratch + (size_t)it * 512;
    a0 += p[t];
    if (c1 <= 480) a1 += p[c1];
  }
  if (c1 == 480) snrm = a1;
  __syncthreads();
  float inv = 1.0f / fmaxf(snrm, 1e-8f);
  out[(size_t)g * 480 + t] = a0 * inv;
  if (c1 < 480) out[(size_t)g * 480 + c1] = a1 * inv;
}

extern "C" void kernel_launch(void* const* d_in, const int* in_sizes, int n_in,
                              void* d_out, int out_size, void* d_ws, size_t ws_size,
                              hipStream_t stream) {
  const float* f   = (const float*)d_in[0];
  const float* Wv0 = (const float*)d_in[7];
  const float* Wv1 = (const float*)d_in[8];
  const float* Wv2 = (const float*)d_in[9];
  const int* batch = (const int*)d_in[13];

  int N = in_sizes[0] / D_TOT;
  int G = out_size / D_TOT;

  // ws byte layout:
  //   [0, 86016)        Mtmp fp32 (21504)
  //   [86016, 172032)   Bpack bf16 (43008)
  //   [172032, 176640)  gptr int[G+1]
  //   [176640, 181248)  itembase int[G+1]
  //   [181248, 181504)  ntot int
  //   [181504, 262144)  items int2[maxItems]
  //   [262144, ...)     scratch float[maxItems*512]
  char* wsb = (char*)d_ws;
  float* Mtmp = (float*)wsb;
  unsigned short* Bpack = (unsigned short*)(wsb + 86016);
  int* gptr = (int*)(wsb + 172032);
  int* itembase = (int*)(wsb + 176640);
  int* ntot = (int*)(wsb + 181248);
  int2* items = (int2*)(wsb + 181504);
  float* scratch = (float*)(wsb + 262144);

  build_gptr<<<(G + 1 + 255) / 256, 256, 0, stream>>>(batch, gptr, N, G);
  build_items_meta<<<1, 1024, 0, stream>>>(gptr, itembase, ntot, G);
  fill_items<<<(G + 255) / 256, 256, 0, stream>>>(gptr, itembase, items, G);

  precompute_M<<<14, 256, 0, stream>>>(
      (const float*)d_in[1], (const float*)d_in[2], (const float*)d_in[3],
      (const float*)d_in[4], (const float*)d_in[5], (const float*)d_in[6],
      (const float*)d_in[10], (const float*)d_in[11], (const float*)d_in[12], Mtmp);

  pack_B<<<(43008 + 255) / 256, 256, 0, stream>>>(Mtmp, Wv0, Wv1, Wv2, Bpack);

  int maxItems = (N + 63) / 64 + G;   // upper bound on graph-aligned items
  fused_partial_kernel<<<(maxItems + 3) / 4, 256, 0, stream>>>(
      f, Bpack, items, ntot, scratch);

  reduce_kernel<<<G, 256, 0, stream>>>(scratch, itembase, (float*)d_out, G);
}

// Round 7
// 435.995 us; speedup vs baseline: 2.7440x; 2.7440x over previous
//
#include <hip/hip_runtime.h>
#include <math.h>

#define D_TOT 480

typedef short bf16x8 __attribute__((ext_vector_type(8)));
typedef float f32x4 __attribute__((ext_vector_type(4)));
typedef float floatx4 __attribute__((ext_vector_type(4)));

#define MFMA16(a, b, c) __builtin_amdgcn_mfma_f32_16x16x32_bf16((a), (b), (c), 0, 0, 0)

static __device__ __forceinline__ unsigned short f2bf(float x) {
  unsigned u = __float_as_uint(x);
  u += 0x7FFFu + ((u >> 16) & 1u);   // RNE (inputs finite)
  return (unsigned short)(u >> 16);
}
static __device__ __forceinline__ float bf2f(unsigned short v) {
  return __uint_as_float(((unsigned)v) << 16);
}

// ---------------------------------------------------------------------------
// K0: Mtmp_b = (Wq_b . Wd_b . Wk_b^T) * scale_b (fp32), scale folds all norms:
//   scale_b = 1 / (m^2 * sqrt(1440*d)).
// ws fp32 layout: M0 [0,16384), M1 [16384,20480), M2 [20480,21504)
// ---------------------------------------------------------------------------
__global__ __launch_bounds__(256) void precompute_M(
    const float* __restrict__ Wq0, const float* __restrict__ Wq1, const float* __restrict__ Wq2,
    const float* __restrict__ Wk0, const float* __restrict__ Wk1, const float* __restrict__ Wk2,
    const float* __restrict__ Wd0, const float* __restrict__ Wd1, const float* __restrict__ Wd2,
    float* __restrict__ ws) {
  __shared__ float T[16 * 128];
  int b = blockIdx.x;
  const float *Wq, *Wk, *Wd;
  float* M;
  int m, deg, strip;
  if (b < 8)       { Wq = Wq0; Wk = Wk0; Wd = Wd0; M = ws;         m = 128; deg = 1; strip = b; }
  else if (b < 12) { Wq = Wq1; Wk = Wk1; Wd = Wd1; M = ws + 16384; m = 64;  deg = 3; strip = b - 8; }
  else if (b < 14) { Wq = Wq2; Wk = Wk2; Wd = Wd2; M = ws + 20480; m = 32;  deg = 5; strip = b - 12; }
  else return;
  int r0 = strip * 16;
  if (r0 >= m) return;
  float scale = 1.0f / ((float)m * (float)m * sqrtf(1440.0f * (float)deg));
  for (int idx = threadIdx.x; idx < 16 * m; idx += 256) {
    int r = idx / m, c = idx % m;
    float s = 0.f;
    for (int a = 0; a < m; ++a) s += Wq[(r0 + r) * m + a] * Wd[a * m + c];
    T[r * m + c] = s;
  }
  __syncthreads();
  for (int idx = threadIdx.x; idx < 16 * m; idx += 256) {
    int r = idx / m, j = idx % m;
    float s = 0.f;
    for (int c = 0; c < m; ++c) s += T[r * m + c] * Wk[j * m + c];
    M[(r0 + r) * m + j] = s * scale;
  }
}

// ---------------------------------------------------------------------------
// K0b: pack B = [M_b | Wv_b/sqrt(m)] (bf16) in per-MFMA-fragment layout.
// Fragment = 1 KB: elem (l,j) = B[k = kt*32+(l>>4)*8+j][c = ct*16+(l&15)].
// ---------------------------------------------------------------------------
__global__ __launch_bounds__(256) void pack_B(
    const float* __restrict__ Mtmp,
    const float* __restrict__ Wv0, const float* __restrict__ Wv1, const float* __restrict__ Wv2,
    unsigned short* __restrict__ Bp) {
  int idx = blockIdx.x * 256 + threadIdx.x;
  if (idx >= 43008) return;
  float val;
  if (idx < 32768) {
    int fragi = idx >> 9, rem = idx & 511;
    int l = rem >> 3, j = rem & 7;
    int ct = fragi >> 2, kt = fragi & 3;
    int k = kt * 32 + (l >> 4) * 8 + j;
    int c = ct * 16 + (l & 15);
    val = (c < 128) ? Mtmp[k * 128 + c] : Wv0[k * 128 + (c - 128)] * 0.08838834764831845f;
  } else if (idx < 40960) {
    int i1 = idx - 32768;
    int fragi = i1 >> 9, rem = i1 & 511;
    int l = rem >> 3, j = rem & 7;
    int ct = fragi >> 1, kt = fragi & 1;
    int k = kt * 32 + (l >> 4) * 8 + j;
    int c = ct * 16 + (l & 15);
    val = (c < 64) ? Mtmp[16384 + k * 64 + c] : Wv1[k * 64 + (c - 64)] * 0.125f;
  } else {
    int i2 = idx - 40960;
    int ct = i2 >> 9, rem = i2 & 511;
    int l = rem >> 3, j = rem & 7;
    int k = (l >> 4) * 8 + j;
    int c = ct * 16 + (l & 15);
    val = (c < 32) ? Mtmp[20480 + k * 32 + c] : Wv2[k * 32 + (c - 32)] * 0.17677669529663687f;
  }
  Bp[idx] = f2bf(val);
}

// ---------------------------------------------------------------------------
// Fused MFMA kernel, one 16-node tile per wave (12500 waves at N=200000),
// strict dispatch-order mapping (block b covers nodes [64b, 64b+64)).
// LDS: natural layout, row = node (1024 B), XOR swizzle byte^=(node&7)<<4.
// f staged with NON-TEMPORAL loads (read-once stream; keep B/outnum in L2).
// Flush: block-uniform fast path (one 481-atomic flush per block) when all
// 64 nodes are one graph; per-wave segmented flush otherwise (R4 verbatim).
// ---------------------------------------------------------------------------
__global__ __launch_bounds__(256, 2) void fused_mfma_kernel(
    const float* __restrict__ f, const unsigned short* __restrict__ Bpack,
    const int* __restrict__ batch,
    float* __restrict__ outnum, float* __restrict__ norm, int N) {
  __shared__ __align__(16) unsigned short xs_all[4 * 8192];
  int t = threadIdx.x;
  int w = t >> 6, lane = t & 63;
  char* xsb = (char*)(xs_all + w * 8192);

  int wid = blockIdx.x * 4 + w;
  int nt = wid * 16;
  if (nt >= N) return;
  int valid = min(16, N - nt);

  int q = lane >> 4, lm = lane & 15;
  unsigned swzlm = (unsigned)((lm & 7) << 4);

  const bf16x8* B0f = (const bf16x8*)Bpack;
  const bf16x8* B1f = (const bf16x8*)(Bpack + 32768);
  const bf16x8* B2f = (const bf16x8*)(Bpack + 40960);

  // block-uniform predicate (same value for all threads of the block)
  int blockbase = blockIdx.x * 64;
  bool uni = (blockbase + 63 < N) && (batch[blockbase] == batch[blockbase + 63]);

  // ---- stage: 16 nodes x 480 fp32 -> natural bf16 rows (swizzled), NT loads ----
  {
    int ns = lane >> 2, e0 = lane & 3;
    const floatx4* frow4 = reinterpret_cast<const floatx4*>(f + (size_t)(nt + ns) * 480);
    char* wrow = xsb + ns * 1024;
    unsigned swzw = (unsigned)((ns & 7) << 4);
    bool okn = ns < valid;
#pragma unroll
    for (int i = 0; i < 30; ++i) {
      int e4 = e0 + i * 4;
      floatx4 xv = {0.f, 0.f, 0.f, 0.f};
      if (okn) xv = __builtin_nontemporal_load(frow4 + e4);
      unsigned p0 = (unsigned)f2bf(xv[0]) | ((unsigned)f2bf(xv[1]) << 16);
      unsigned p1 = (unsigned)f2bf(xv[2]) | ((unsigned)f2bf(xv[3]) << 16);
      *reinterpret_cast<uint2*>(wrow + (((unsigned)(e4 * 8)) ^ swzw)) = make_uint2(p0, p1);
    }
  }

  // ---- gather A-frags into registers (row = lm, k-chunk = q) ----
  const char* arow = xsb + lm * 1024;
  bf16x8 a0[4];
#pragma unroll
  for (int ks = 0; ks < 4; ++ks)
    a0[ks] = *reinterpret_cast<const bf16x8*>(arow + (((unsigned)(ks * 64 + q * 16)) ^ swzlm));
  bf16x8 a1[3][2];
#pragma unroll
  for (int d = 0; d < 3; ++d)
#pragma unroll
    for (int h = 0; h < 2; ++h) {
      bf16x8 v;
#pragma unroll
      for (int j = 0; j < 8; ++j) {
        int km = h * 32 + q * 8 + j;
        unsigned off = ((unsigned)(2 * (128 + 3 * km + d))) ^ swzlm;
        v[j] = (short)*reinterpret_cast<const unsigned short*>(arow + off);
      }
      a1[d][h] = v;
    }
  bf16x8 a2[5];
#pragma unroll
  for (int d = 0; d < 5; ++d) {
    bf16x8 v;
#pragma unroll
    for (int j = 0; j < 8; ++j) {
      int km = q * 8 + j;
      unsigned off = ((unsigned)(2 * (320 + 5 * km + d))) ^ swzlm;
      v[j] = (short)*reinterpret_cast<const unsigned short*>(arow + off);
    }
    a2[d] = v;
  }

  // x read in C-frag order for the logit dot: node = q*4+r, natural col c
  auto ldx = [&](int node, int c) -> float {
    unsigned off = ((unsigned)(2 * c)) ^ ((unsigned)((node & 7) << 4));
    return bf2f(*reinterpret_cast<const unsigned short*>(xsb + node * 1024 + off));
  };

  // ---- u-phase: logits ----
  float pl0 = 0.f, pl1 = 0.f, pl2 = 0.f, pl3 = 0.f;
#pragma unroll
  for (int ct = 0; ct < 8; ++ct) {
    f32x4 u = {0.f, 0.f, 0.f, 0.f};
    u = MFMA16(a0[0], B0f[(ct * 4 + 0) * 64 + lane], u);
    u = MFMA16(a0[1], B0f[(ct * 4 + 1) * 64 + lane], u);
    u = MFMA16(a0[2], B0f[(ct * 4 + 2) * 64 + lane], u);
    u = MFMA16(a0[3], B0f[(ct * 4 + 3) * 64 + lane], u);
    int c = ct * 16 + lm;
    pl0 += u[0] * ldx(q * 4 + 0, c);
    pl1 += u[1] * ldx(q * 4 + 1, c);
    pl2 += u[2] * ldx(q * 4 + 2, c);
    pl3 += u[3] * ldx(q * 4 + 3, c);
  }
#pragma unroll
  for (int d = 0; d < 3; ++d)
#pragma unroll
    for (int ct = 0; ct < 4; ++ct) {
      f32x4 u = {0.f, 0.f, 0.f, 0.f};
      u = MFMA16(a1[d][0], B1f[(ct * 2 + 0) * 64 + lane], u);
      u = MFMA16(a1[d][1], B1f[(ct * 2 + 1) * 64 + lane], u);
      int c = 128 + 3 * (ct * 16 + lm) + d;
      pl0 += u[0] * ldx(q * 4 + 0, c);
      pl1 += u[1] * ldx(q * 4 + 1, c);
      pl2 += u[2] * ldx(q * 4 + 2, c);
      pl3 += u[3] * ldx(q * 4 + 3, c);
    }
#pragma unroll
  for (int d = 0; d < 5; ++d)
#pragma unroll
    for (int ct = 0; ct < 2; ++ct) {
      f32x4 u = {0.f, 0.f, 0.f, 0.f};
      u = MFMA16(a2[d], B2f[ct * 64 + lane], u);
      int c = 320 + 5 * (ct * 16 + lm) + d;
      pl0 += u[0] * ldx(q * 4 + 0, c);
      pl1 += u[1] * ldx(q * 4 + 1, c);
      pl2 += u[2] * ldx(q * 4 + 2, c);
      pl3 += u[3] * ldx(q * 4 + 3, c);
    }
#pragma unroll
  for (int off = 1; off < 16; off <<= 1) {
    pl0 += __shfl_xor(pl0, off);
    pl1 += __shfl_xor(pl1, off);
    pl2 += __shfl_xor(pl2, off);
    pl3 += __shfl_xor(pl3, off);
  }
  float w0 = (q * 4 + 0 < valid) ? __expf(pl0) : 0.f;
  float w1 = (q * 4 + 1 < valid) ? __expf(pl1) : 0.f;
  float w2 = (q * 4 + 2 < valid) ? __expf(pl2) : 0.f;
  float w3 = (q * 4 + 3 < valid) ? __expf(pl3) : 0.f;

  // ---- v accumulators ----
  float r0[8], r1[3][4], r2[5][2], naccw = 0.f;
#pragma unroll
  for (int i = 0; i < 8; ++i) r0[i] = 0.f;
#pragma unroll
  for (int d = 0; d < 3; ++d)
#pragma unroll
    for (int i = 0; i < 4; ++i) r1[d][i] = 0.f;
#pragma unroll
  for (int d = 0; d < 5; ++d)
#pragma unroll
    for (int i = 0; i < 2; ++i) r2[d][i] = 0.f;

  auto vpass = [&](float vw0, float vw1, float vw2, float vw3) {
    if (lm == 0) naccw += vw0 + vw1 + vw2 + vw3;
#pragma unroll
    for (int ct = 0; ct < 8; ++ct) {
      f32x4 v = {0.f, 0.f, 0.f, 0.f};
      v = MFMA16(a0[0], B0f[((ct + 8) * 4 + 0) * 64 + lane], v);
      v = MFMA16(a0[1], B0f[((ct + 8) * 4 + 1) * 64 + lane], v);
      v = MFMA16(a0[2], B0f[((ct + 8) * 4 + 2) * 64 + lane], v);
      v = MFMA16(a0[3], B0f[((ct + 8) * 4 + 3) * 64 + lane], v);
      r0[ct] += vw0 * v[0] + vw1 * v[1] + vw2 * v[2] + vw3 * v[3];
    }
#pragma unroll
    for (int d = 0; d < 3; ++d)
#pragma unroll
      for (int ct = 0; ct < 4; ++ct) {
        f32x4 v = {0.f, 0.f, 0.f, 0.f};
        v = MFMA16(a1[d][0], B1f[((ct + 4) * 2 + 0) * 64 + lane], v);
        v = MFMA16(a1[d][1], B1f[((ct + 4) * 2 + 1) * 64 + lane], v);
        r1[d][ct] += vw0 * v[0] + vw1 * v[1] + vw2 * v[2] + vw3 * v[3];
      }
#pragma unroll
    for (int d = 0; d < 5; ++d)
#pragma unroll
      for (int ct = 0; ct < 2; ++ct) {
        f32x4 v = {0.f, 0.f, 0.f, 0.f};
        v = MFMA16(a2[d], B2f[(ct + 2) * 64 + lane], v);
        r2[d][ct] += vw0 * v[0] + vw1 * v[1] + vw2 * v[2] + vw3 * v[3];
      }
  };

  auto wavered = [&](float s) -> float {
    s += __shfl_xor(s, 16);
    s += __shfl_xor(s, 32);
    return s;
  };

  if (uni) {
    // ---- fast path: whole block is one graph; combine 4 waves in LDS ----
    vpass(w0, w1, w2, w3);
    __syncthreads();                      // x-tiles dead now
    float* buf = (float*)xs_all;          // [4][496]
#pragma unroll
    for (int ct = 0; ct < 8; ++ct) {
      float sv = wavered(r0[ct]);
      if (lane < 16) buf[w * 496 + ct * 16 + lane] = sv;
    }
#pragma unroll
    for (int d = 0; d < 3; ++d)
#pragma unroll
      for (int ct = 0; ct < 4; ++ct) {
        float sv = wavered(r1[d][ct]);
        if (lane < 16) buf[w * 496 + 128 + 3 * (ct * 16 + lane) + d] = sv;
      }
#pragma unroll
    for (int d = 0; d < 5; ++d)
#pragma unroll
      for (int ct = 0; ct < 2; ++ct) {
        float sv = wavered(r2[d][ct]);
        if (lane < 16) buf[w * 496 + 320 + 5 * (ct * 16 + lane) + d] = sv;
      }
    {
      float sw = wavered(naccw);
      if (lane == 0) buf[w * 496 + 480] = sw;
    }
    __syncthreads();
    int gg = batch[blockbase];
    float* og = outnum + (size_t)gg * 480;
    for (int c = t; c < 480; c += 256) {
      float s = buf[c] + buf[496 + c] + buf[992 + c] + buf[1488 + c];
      atomicAdd(og + c, s);
    }
    if (t == 0) {
      float s = buf[480] + buf[976] + buf[1472] + buf[1968];
      atomicAdd(norm + gg, s);
    }
  } else {
    // ---- general path: per-wave segmented flush (R4 verbatim) ----
    auto flushf = [&](int g) {
      float* og = outnum + (size_t)g * 480;
#pragma unroll
      for (int ct = 0; ct < 8; ++ct) {
        float s = wavered(r0[ct]);
        if (lane < 16) atomicAdd(og + ct * 16 + lane, s);
        r0[ct] = 0.f;
      }
#pragma unroll
      for (int d = 0; d < 3; ++d)
#pragma unroll
        for (int ct = 0; ct < 4; ++ct) {
          float s = wavered(r1[d][ct]);
          if (lane < 16) atomicAdd(og + 128 + 3 * (ct * 16 + lane) + d, s);
          r1[d][ct] = 0.f;
        }
#pragma unroll
      for (int d = 0; d < 5; ++d)
#pragma unroll
        for (int ct = 0; ct < 2; ++ct) {
          float s = wavered(r2[d][ct]);
          if (lane < 16) atomicAdd(og + 320 + 5 * (ct * 16 + lane) + d, s);
          r2[d][ct] = 0.f;
        }
      float sw = wavered(naccw);
      if (lane == 0) atomicAdd(norm + g, sw);
      naccw = 0.f;
    };

    int gl = batch[nt + (lm < valid ? lm : valid - 1)];
    int gp = __shfl(gl, (lane == 0) ? 0 : lane - 1);
    unsigned long long bm = __ballot(lm > 0 && lm < valid && gl != gp);
    unsigned segm = (unsigned)bm & 0xFFFEu;

    int cur_g = -1;
    int a = 0;
    while (a < valid) {
      unsigned hi = segm & ~((1u << (a + 1)) - 1u);
      int b = hi ? (int)__builtin_ctz(hi) : valid;
      int gs = __shfl(gl, a);
      if (cur_g >= 0) flushf(cur_g);
      cur_g = gs;
      int nq = q * 4;
      float m0 = (nq + 0 >= a && nq + 0 < b) ? w0 : 0.f;
      float m1 = (nq + 1 >= a && nq + 1 < b) ? w1 : 0.f;
      float m2 = (nq + 2 >= a && nq + 2 < b) ? w2 : 0.f;
      float m3 = (nq + 3 >= a && nq + 3 < b) ? w3 : 0.f;
      vpass(m0, m1, m2, m3);
      a = b;
    }
    if (cur_g >= 0) flushf(cur_g);
  }
}

// ---------------------------------------------------------------------------
// finalize: out = num / max(norm, 1e-8)
// ---------------------------------------------------------------------------
__global__ __launch_bounds__(256) void finalize_kernel(
    float* __restrict__ out, const float* __restrict__ norm, int total) {
  int idx = blockIdx.x * blockDim.x + threadIdx.x;
  if (idx < total) {
    int g = idx / 480;
    out[idx] = out[idx] / fmaxf(norm[g], 1e-8f);
  }
}

extern "C" void kernel_launch(void* const* d_in, const int* in_sizes, int n_in,
                              void* d_out, int out_size, void* d_ws, size_t ws_size,
                              hipStream_t stream) {
  const float* f   = (const float*)d_in[0];
  const float* Wv0 = (const float*)d_in[7];
  const float* Wv1 = (const float*)d_in[8];
  const float* Wv2 = (const float*)d_in[9];
  const int* batch = (const int*)d_in[13];

  int N = in_sizes[0] / D_TOT;
  int G = out_size / D_TOT;

  // ws bytes: [0,86016) Mtmp fp32; [86016,172032) Bpack bf16; [172032,..) norm
  float* Mtmp = (float*)d_ws;
  unsigned short* Bpack = (unsigned short*)((char*)d_ws + 86016);
  float* norm = (float*)((char*)d_ws + 172032);
  float* out  = (float*)d_out;

  hipMemsetAsync(d_out, 0, (size_t)out_size * sizeof(float), stream);
  hipMemsetAsync(norm, 0, (size_t)G * sizeof(float), stream);

  precompute_M<<<14, 256, 0, stream>>>(
      (const float*)d_in[1], (const float*)d_in[2], (const float*)d_in[3],
      (const float*)d_in[4], (const float*)d_in[5], (const float*)d_in[6],
      (const float*)d_in[10], (const float*)d_in[11], (const float*)d_in[12], Mtmp);

  pack_B<<<(43008 + 255) / 256, 256, 0, stream>>>(Mtmp, Wv0, Wv1, Wv2, Bpack);

  int nwaves = (N + 15) / 16;
  int nblocks = (nwaves + 3) / 4;
  fused_mfma_kernel<<<nblocks, 256, 0, stream>>>(f, Bpack, batch, out, norm, N);

  finalize_kernel<<<(G * D_TOT + 255) / 256, 256, 0, stream>>>(out, norm, G * D_TOT);
}